// Round 1
// 798.603 us; speedup vs baseline: 1.0698x; 1.0698x over previous
//
#include <hip/hip_runtime.h>
#include <hip/hip_bf16.h>

// Problem constants (RoutedExperts: N=16384, D=2048, H=1024, E=16)
#define NE 16
#define NT 1024   // tokens per expert
#define ND 2048   // model dim
#define NH 1024   // hidden dim

typedef __bf16 bf16x8 __attribute__((ext_vector_type(8)));
typedef __bf16 bf16x4 __attribute__((ext_vector_type(4)));
typedef float  f32x4  __attribute__((ext_vector_type(4)));

// ---------------------------------------------------------------------------
// async global->LDS, 16B per lane. LDS dest is wave-uniform base + lane*16.
// ---------------------------------------------------------------------------
__device__ __forceinline__ void async_load16(const __bf16* g, __bf16* l) {
  __builtin_amdgcn_global_load_lds(
      (const __attribute__((address_space(1))) void*)g,
      (__attribute__((address_space(3))) void*)l, 16, 0, 0);
}

// ---------------------------------------------------------------------------
// 256x256-tile NT GEMM, bf16 in: C[m][n] = sum_k A[m][k]*B[n][k].
// BK=32, 512 threads (8 waves, 2Mx4N), per-wave 128x64 output.
// 4-deep LDS ring (4 x (A 16KiB + B 16KiB) = 128 KiB), counted vmcnt(8):
//   prologue stages tiles 0..2; iter t waits vmcnt(8) (tiles t+1,t+2 in
//   flight), ONE raw s_barrier per tile, then stages tile t+3 into the ring
//   slot whose readers all finished before this barrier.
// T2 swizzle: global_load_lds dest is linear; SOURCE col pre-permuted with
//   (tid&3)^((tid>>3)&3); ds_read applies same involution slot^((row>>1)&3).
//   -> 64-lane ds_read_b128 spreads over all 8 16B slots (2-way = free).
// ldc = 2048 for both call sites. CBF16: write bf16 else fp32.
// ---------------------------------------------------------------------------
template<bool CBF16>
__global__ __launch_bounds__(512, 2)
void gemm_nt_256(const __bf16* __restrict__ Ap, const __bf16* __restrict__ Bp,
                 void* __restrict__ Cp, int K, long sA, long sB, long sC)
{
  __shared__ __bf16 sm[4 * 16384];   // ring of 4: [A 8192 elems][B 8192 elems]

  const int tid  = threadIdx.x;
  const int lane = tid & 63;
  const int wave = tid >> 6;
  const int wr = wave >> 2, wc = wave & 3;   // 2 x 4 wave grid
  const int m0 = blockIdx.y * 256;
  const int n0 = blockIdx.x * 256;
  const long zb = blockIdx.z;

  const __bf16* A = Ap + zb * sA + (long)m0 * K;
  const __bf16* B = Bp + zb * sB + (long)n0 * K;

  // staging: thread covers LDS bytes tid*16 of each 8 KiB half
  // -> LDS (row = tid>>2, slot = tid&3); source col pre-swizzled so that
  //    LDS physical slot s of row r holds logical slot s^((r>>1)&3).
  const int srow = tid >> 2;                              // 0..127
  const int scol = ((tid & 3) ^ ((tid >> 3) & 3)) * 8;    // pre-swizzled col
  const __bf16* As0 = A + (long)srow * K + scol;
  const __bf16* Bs0 = B + (long)srow * K + scol;
  const long h1 = (long)128 * K;                          // second 128-row half
  __bf16* ldst = &sm[wave * 512];                         // wave-uniform base

  const int KT = K >> 5;

  // frag-read offsets: logical slot = lane>>4, row low bits give the XOR
  const int l15 = lane & 15;
  const int rsl = ((lane >> 4) ^ ((l15 >> 1) & 3)) * 8;   // swizzled elem off

  f32x4 acc[8][4] = {};

  auto stage = [&](int t) {
    const int bb  = (t & 3) * 16384;
    const long kk = (long)(t << 5);
    async_load16(As0 + kk,      ldst + bb);
    async_load16(As0 + kk + h1, ldst + bb + 4096);
    async_load16(Bs0 + kk,      ldst + bb + 8192);
    async_load16(Bs0 + kk + h1, ldst + bb + 12288);
  };

  stage(0); stage(1); stage(2);

  for (int t = 0; t < KT; ++t) {
    // tile t must be landed; tiles t+1, t+2 (8 wave-loads) stay in flight
    if (t < KT - 2)       asm volatile("s_waitcnt vmcnt(8)" ::: "memory");
    else if (t == KT - 2) asm volatile("s_waitcnt vmcnt(4)" ::: "memory");
    else                  asm volatile("s_waitcnt vmcnt(0)" ::: "memory");
    __builtin_amdgcn_s_barrier();        // raw barrier: no vmcnt(0) drain
    __builtin_amdgcn_sched_barrier(0);
    if (t + 3 < KT) stage(t + 3);        // slot (t-1)&3: readers done pre-barrier

    const int bb = (t & 3) * 16384;
    bf16x8 af[8], bq[4];
    #pragma unroll
    for (int i = 0; i < 8; ++i)
      af[i] = *(const bf16x8*)(&sm[bb + (wr * 128 + i * 16 + l15) * 32 + rsl]);
    #pragma unroll
    for (int j = 0; j < 4; ++j)
      bq[j] = *(const bf16x8*)(&sm[bb + 8192 + (wc * 64 + j * 16 + l15) * 32 + rsl]);

    __builtin_amdgcn_s_setprio(1);
    #pragma unroll
    for (int i = 0; i < 8; ++i)
      #pragma unroll
      for (int j = 0; j < 4; ++j)
        acc[i][j] = __builtin_amdgcn_mfma_f32_16x16x32_bf16(af[i], bq[j], acc[i][j], 0, 0, 0);
    __builtin_amdgcn_s_setprio(0);
  }

  // epilogue: C/D layout col = lane&15, row = (lane>>4)*4 + reg
  const int rq = (lane >> 4) * 4;
  if constexpr (CBF16) {
    __bf16* C = (__bf16*)Cp + zb * sC;
    #pragma unroll
    for (int i = 0; i < 8; ++i)
      #pragma unroll
      for (int j = 0; j < 4; ++j)
        #pragma unroll
        for (int r = 0; r < 4; ++r)
          C[(long)(m0 + wr * 128 + i * 16 + rq + r) * 2048 +
            (n0 + wc * 64 + j * 16 + l15)] = (__bf16)acc[i][j][r];
  } else {
    float* C = (float*)Cp + zb * sC;
    #pragma unroll
    for (int i = 0; i < 8; ++i)
      #pragma unroll
      for (int j = 0; j < 4; ++j)
        #pragma unroll
        for (int r = 0; r < 4; ++r)
          C[(long)(m0 + wr * 128 + i * 16 + rq + r) * 2048 +
            (n0 + wc * 64 + j * 16 + l15)] = acc[i][j][r];
  }
}

// ---------------------------------------------------------------------------
// Fallback (round-1) NT GEMM with in-kernel fp32->bf16 staging.
// ---------------------------------------------------------------------------
constexpr int LDSS = 40;
template<bool AF32, bool BF32, bool CBF16>
__global__ __launch_bounds__(256, 2)
void gemm_nt(const void* __restrict__ Ap, const void* __restrict__ Bp,
             void* __restrict__ Cp, int K, long sA, long sB, long sC)
{
  __shared__ __bf16 As[128 * LDSS];
  __shared__ __bf16 Bs[128 * LDSS];
  const int tid  = threadIdx.x;
  const int lane = tid & 63;
  const int wave = tid >> 6;
  const int wr = wave >> 1, wc = wave & 1;
  const int m0 = blockIdx.y * 128;
  const int n0 = blockIdx.x * 128;
  const long zb = blockIdx.z;
  f32x4 acc[4][4] = {};
  const int kq  = (lane >> 4) * 8;
  const int l15 = lane & 15;

  for (int kk = 0; kk < K; kk += 32) {
    if constexpr (AF32) {
      const float* A = (const float*)Ap + zb * sA + (long)m0 * K + kk;
      #pragma unroll
      for (int p = 0; p < 4; ++p) {
        const int r = p * 32 + (tid >> 3);
        const int c = (tid & 7) * 4;
        const float4 v = *(const float4*)(A + (long)r * K + c);
        bf16x4 w;
        w[0] = (__bf16)v.x; w[1] = (__bf16)v.y; w[2] = (__bf16)v.z; w[3] = (__bf16)v.w;
        *(bf16x4*)(&As[r * LDSS + c]) = w;
      }
    } else {
      const __bf16* A = (const __bf16*)Ap + zb * sA + (long)m0 * K + kk;
      #pragma unroll
      for (int p = 0; p < 2; ++p) {
        const int r = p * 64 + (tid >> 2);
        const int c = (tid & 3) * 8;
        *(bf16x8*)(&As[r * LDSS + c]) = *(const bf16x8*)(A + (long)r * K + c);
      }
    }
    if constexpr (BF32) {
      const float* B = (const float*)Bp + zb * sB + (long)n0 * K + kk;
      #pragma unroll
      for (int p = 0; p < 4; ++p) {
        const int r = p * 32 + (tid >> 3);
        const int c = (tid & 7) * 4;
        const float4 v = *(const float4*)(B + (long)r * K + c);
        bf16x4 w;
        w[0] = (__bf16)v.x; w[1] = (__bf16)v.y; w[2] = (__bf16)v.z; w[3] = (__bf16)v.w;
        *(bf16x4*)(&Bs[r * LDSS + c]) = w;
      }
    } else {
      const __bf16* B = (const __bf16*)Bp + zb * sB + (long)n0 * K + kk;
      #pragma unroll
      for (int p = 0; p < 2; ++p) {
        const int r = p * 64 + (tid >> 2);
        const int c = (tid & 3) * 8;
        *(bf16x8*)(&Bs[r * LDSS + c]) = *(const bf16x8*)(B + (long)r * K + c);
      }
    }
    __syncthreads();
    bf16x8 af[4], bq[4];
    #pragma unroll
    for (int i = 0; i < 4; ++i)
      af[i] = *(const bf16x8*)(&As[(wr * 64 + i * 16 + l15) * LDSS + kq]);
    #pragma unroll
    for (int j = 0; j < 4; ++j)
      bq[j] = *(const bf16x8*)(&Bs[(wc * 64 + j * 16 + l15) * LDSS + kq]);
    #pragma unroll
    for (int i = 0; i < 4; ++i)
      #pragma unroll
      for (int j = 0; j < 4; ++j)
        acc[i][j] = __builtin_amdgcn_mfma_f32_16x16x32_bf16(af[i], bq[j], acc[i][j], 0, 0, 0);
    __syncthreads();
  }
  const int rq = (lane >> 4) * 4;
  if constexpr (CBF16) {
    __bf16* C = (__bf16*)Cp + zb * sC;
    #pragma unroll
    for (int i = 0; i < 4; ++i)
      #pragma unroll
      for (int j = 0; j < 4; ++j)
        #pragma unroll
        for (int r = 0; r < 4; ++r)
          C[(long)(m0 + wr * 64 + i * 16 + rq + r) * 2048 +
            (n0 + wc * 64 + j * 16 + l15)] = (__bf16)acc[i][j][r];
  } else {
    float* C = (float*)Cp + zb * sC;
    #pragma unroll
    for (int i = 0; i < 4; ++i)
      #pragma unroll
      for (int j = 0; j < 4; ++j)
        #pragma unroll
        for (int r = 0; r < 4; ++r)
          C[(long)(m0 + wr * 64 + i * 16 + rq + r) * 2048 +
            (n0 + wc * 64 + j * 16 + l15)] = acc[i][j][r];
  }
}

// ---------------------------------------------------------------------------
// fp32 -> bf16 elementwise cast, 8 elems/thread
// ---------------------------------------------------------------------------
__global__ __launch_bounds__(256)
void cast_f32_bf16(const float* __restrict__ src, __bf16* __restrict__ dst)
{
  const long i = ((long)blockIdx.x * 256 + threadIdx.x) * 8;
  const float4 a = *(const float4*)(src + i);
  const float4 b = *(const float4*)(src + i + 4);
  bf16x8 o;
  o[0] = (__bf16)a.x; o[1] = (__bf16)a.y; o[2] = (__bf16)a.z; o[3] = (__bf16)a.w;
  o[4] = (__bf16)b.x; o[5] = (__bf16)b.y; o[6] = (__bf16)b.z; o[7] = (__bf16)b.w;
  *(bf16x8*)(dst + i) = o;
}

// ---------------------------------------------------------------------------
// w_down (E,H,D) fp32 -> wdT (E,D,H) bf16
// ---------------------------------------------------------------------------
__global__ __launch_bounds__(256)
void transpose_cast_wdown(const float* __restrict__ w, __bf16* __restrict__ wt)
{
  __shared__ __bf16 lt[64][72];
  const int e  = blockIdx.z;
  const int hb = blockIdx.y * 64;
  const int db = blockIdx.x * 64;
  const int tid = threadIdx.x;
  const int r  = tid >> 2;
  const int cq = (tid & 3) * 16;

  const float* src = w + (long)e * NH * ND + (long)(hb + r) * ND + db + cq;
  #pragma unroll
  for (int q = 0; q < 4; ++q) {
    const float4 v = *(const float4*)(src + q * 4);
    lt[cq + q * 4 + 0][r] = (__bf16)v.x;
    lt[cq + q * 4 + 1][r] = (__bf16)v.y;
    lt[cq + q * 4 + 2][r] = (__bf16)v.z;
    lt[cq + q * 4 + 3][r] = (__bf16)v.w;
  }
  __syncthreads();
  __bf16* dst = wt + (long)e * ND * NH + (long)(db + r) * NH + hb + cq;
  *(bf16x8*)(dst)     = *(const bf16x8*)(&lt[r][cq]);
  *(bf16x8*)(dst + 8) = *(const bf16x8*)(&lt[r][cq + 8]);
}

// ---------------------------------------------------------------------------
// h = up * silu(gate); ug (E*T, 2H) -> h (E*T, H)
// ---------------------------------------------------------------------------
__global__ __launch_bounds__(256)
void silu_mul(const __bf16* __restrict__ ug, __bf16* __restrict__ h)
{
  const long g  = (long)blockIdx.x * 256 + threadIdx.x;
  const int  c8 = (int)(g & 127) * 8;
  const long row = g >> 7;
  const bf16x8 u  = *(const bf16x8*)(ug + row * 2048 + c8);
  const bf16x8 gt = *(const bf16x8*)(ug + row * 2048 + 1024 + c8);
  bf16x8 o;
  #pragma unroll
  for (int i = 0; i < 8; ++i) {
    const float uu = (float)u[i];
    const float gg = (float)gt[i];
    const float s  = gg / (1.0f + __expf(-gg));
    o[i] = (__bf16)(uu * s);
  }
  *(bf16x8*)(h + row * 1024 + c8) = o;
}

// ---------------------------------------------------------------------------
extern "C" void kernel_launch(void* const* d_in, const int* in_sizes, int n_in,
                              void* d_out, int out_size, void* d_ws, size_t ws_size,
                              hipStream_t stream) {
  const float* x   = (const float*)d_in[0];  // (16384, 2048)
  const float* wug = (const float*)d_in[1];  // (16, 2048, 2048)
  const float* wdn = (const float*)d_in[2];  // (16, 1024, 2048)
  float* out = (float*)d_out;

  const size_t MB = 1024 * 1024;
  char* ws = (char*)d_ws;
  __bf16* wdT = (__bf16*)(ws);             // 64 MiB: (E, D, H) bf16
  __bf16* ug  = (__bf16*)(ws + 64 * MB);   // 64 MiB: (E*T, 2H) bf16
  __bf16* hbf = (__bf16*)(ws + 128 * MB);  // 32 MiB: (E*T, H) bf16

  transpose_cast_wdown<<<dim3(ND / 64, NH / 64, NE), 256, 0, stream>>>(wdn, wdT);

  if (ws_size >= 352 * MB) {
    __bf16* xbf   = (__bf16*)(ws + 160 * MB);  // 64 MiB
    __bf16* wugbf = (__bf16*)(ws + 224 * MB);  // 128 MiB

    cast_f32_bf16<<<16384, 256, 0, stream>>>(x, xbf);        // 33.5M elems
    cast_f32_bf16<<<32768, 256, 0, stream>>>(wug, wugbf);    // 67.1M elems

    gemm_nt_256<true><<<dim3(2 * NH / 256, NT / 256, NE), 512, 0, stream>>>(
        xbf, wugbf, ug, ND, (long)NT * ND, (long)2 * NH * ND, (long)NT * 2 * NH);

    silu_mul<<<(NE * NT * NH / 8) / 256, 256, 0, stream>>>(ug, hbf);

    gemm_nt_256<false><<<dim3(ND / 256, NT / 256, NE), 512, 0, stream>>>(
        hbf, wdT, out, NH, (long)NT * NH, (long)ND * NH, (long)NT * ND);
  } else {
    gemm_nt<true, true, true><<<dim3(2 * NH / 128, NT / 128, NE), 256, 0, stream>>>(
        x, wug, ug, ND, (long)NT * ND, (long)2 * NH * ND, (long)NT * 2 * NH);

    silu_mul<<<(NE * NT * NH / 8) / 256, 256, 0, stream>>>(ug, hbf);

    gemm_nt<false, false, false><<<dim3(ND / 128, NT / 128, NE), 256, 0, stream>>>(
        hbf, wdT, out, NH, (long)NT * NH, (long)ND * NH, (long)NT * ND);
  }
}